// Round 9
// baseline (594.106 us; speedup 1.0000x reference)
//
#include <hip/hip_runtime.h>
#include <stdint.h>

// Problem constants
#define BATCH 2
#define TDIM 2048
#define EDIM 2048
#define NH 16
#define HD 128
#define E3 6144
#define MROWS 4096  // BATCH*TDIM
#define QKS 4096    // row stride of compacted Q|K buffer

typedef short v8bf __attribute__((ext_vector_type(8)));   // 8 bf16 bit patterns (4 VGPRs)
typedef float v4f  __attribute__((ext_vector_type(4)));

typedef __attribute__((address_space(3))) uint8_t lds_u8;
typedef __attribute__((address_space(1))) uint8_t glb_u8;

__device__ __forceinline__ void gload16(const void* g, void* l) {
    __builtin_amdgcn_global_load_lds((const glb_u8*)g, (lds_u8*)l, 16, 0, 0);
}

__device__ __forceinline__ ushort f2bf(float f) {
    uint32_t u = __float_as_uint(f);
    return (ushort)((u + 0x7fffu + ((u >> 16) & 1u)) >> 16);  // RNE
}

// ---------------- fused preprocessing: tcvt(w_qkv) + tcvt(w_out) + cvtx(x) ----------------
__device__ __forceinline__ void tcvt_body(const float* __restrict__ in, ushort* __restrict__ out,
                                          int R, int C, int tcb, int trb, int tid) {
    __shared__ float t[32][33];
    const int tc = tcb * 32, tr = trb * 32;
    const int row = tid >> 3, c4 = (tid & 7) * 4;
    const float4 v = *reinterpret_cast<const float4*>(in + (size_t)(tr + row) * C + tc + c4);
    t[row][c4] = v.x; t[row][c4 + 1] = v.y; t[row][c4 + 2] = v.z; t[row][c4 + 3] = v.w;
    __syncthreads();
    const int oc = tid >> 3, r4 = (tid & 7) * 4;
    ushort4 o = make_ushort4(f2bf(t[r4][oc]), f2bf(t[r4 + 1][oc]),
                             f2bf(t[r4 + 2][oc]), f2bf(t[r4 + 3][oc]));
    *reinterpret_cast<ushort4*>(out + (size_t)(tc + oc) * R + tr + r4) = o;
}

#define NB_T1 12288   // (6144/32)*(2048/32)
#define NB_T2 4096    // (2048/32)*(2048/32)
#define NB_CV 2048

__global__ void prep_kernel(const float* __restrict__ x, const float* __restrict__ w_qkv,
                            const float* __restrict__ w_out, ushort* __restrict__ xb,
                            ushort* __restrict__ wqkvT, ushort* __restrict__ woutT) {
    const int bid = blockIdx.x;
    const int tid = threadIdx.x;
    if (bid < NB_T1) {
        tcvt_body(w_qkv, wqkvT, EDIM, E3, bid % (E3 / 32), bid / (E3 / 32), tid);
    } else if (bid < NB_T1 + NB_T2) {
        const int b2 = bid - NB_T1;
        tcvt_body(w_out, woutT, EDIM, EDIM, b2 % (EDIM / 32), b2 / (EDIM / 32), tid);
    } else {
        const int b3 = bid - NB_T1 - NB_T2;
        int i = (b3 * 256 + tid) * 4;
        const int stride = NB_CV * 256 * 4;
        const int n = MROWS * EDIM;
        for (; i < n; i += stride) {
            const float4 v = *reinterpret_cast<const float4*>(x + i);
            ushort4 o = make_ushort4(f2bf(v.x), f2bf(v.y), f2bf(v.z), f2bf(v.w));
            *reinterpret_cast<ushort4*>(xb + i) = o;
        }
    }
}

// ---------------- bf16 GEMM (128x128, m97-structure, proven 892 TF) ----------------
// MODE 0: bf16 C. MODE 1: f32 C + bias. MODE 2: qkv-split -> Q (pre-scaled by 1/sqrt(d)),K
//         cols to qk (stride QKS), V cols (bn>=32) transposed per-head into vt[bh][d][t].
template <int MODE>
__global__ void gemm_kernel(const ushort* __restrict__ A, const ushort* __restrict__ Bt,
                            void* __restrict__ Cv, const float* __restrict__ bias,
                            ushort* __restrict__ vtout,
                            int Mdim, int Ndim, int Kdim) {
    __shared__ __align__(16) ushort As[128 * 64];
    __shared__ __align__(16) ushort Bs[128 * 64];
    const int tid = threadIdx.x;
    const int lane = tid & 63;
    const int wv = tid >> 6;
    const int l4 = lane >> 4, l16 = lane & 15;
    const int nbn = Ndim >> 7;
    const int nwg = (Mdim >> 7) * nbn;
    int bid = blockIdx.x;
    bid = (bid & 7) * (nwg >> 3) + (bid >> 3);   // XCD swizzle (nwg % 8 == 0)
    const int bm = bid / nbn, bn = bid % nbn;
    const int wr = wv >> 1, wc = wv & 1;

    const ushort* Abase = A + (size_t)(bm * 128) * Kdim;
    const ushort* Bbase = Bt + (size_t)(bn * 128) * Kdim;

    v4f acc[4][4] = {};

    for (int k0 = 0; k0 < Kdim; k0 += 64) {
#pragma unroll
        for (int i = 0; i < 4; ++i) {
            const int c = i * 256 + tid;
            const int row = c >> 3;
            const int kc = (c & 7) ^ (row & 7);    // pre-swizzled global source
            gload16(Abase + (size_t)row * Kdim + k0 + kc * 8, &As[(i * 256 + wv * 64) * 8]);
        }
#pragma unroll
        for (int i = 0; i < 4; ++i) {
            const int c = i * 256 + tid;
            const int row = c >> 3;
            const int kc = (c & 7) ^ (row & 7);
            gload16(Bbase + (size_t)row * Kdim + k0 + kc * 8, &Bs[(i * 256 + wv * 64) * 8]);
        }
        __syncthreads();
#pragma unroll
        for (int kk = 0; kk < 2; ++kk) {
            v8bf af[4], bfr[4];
#pragma unroll
            for (int m = 0; m < 4; ++m) {
                const int r = wr * 64 + m * 16 + l16;
                const int slot = (kk * 4 + l4) ^ (r & 7);
                af[m] = *reinterpret_cast<const v8bf*>(&As[r * 64 + slot * 8]);
            }
#pragma unroll
            for (int n = 0; n < 4; ++n) {
                const int r = wc * 64 + n * 16 + l16;
                const int slot = (kk * 4 + l4) ^ (r & 7);
                bfr[n] = *reinterpret_cast<const v8bf*>(&Bs[r * 64 + slot * 8]);
            }
#pragma unroll
            for (int m = 0; m < 4; ++m)
#pragma unroll
                for (int n = 0; n < 4; ++n)
                    acc[m][n] = __builtin_amdgcn_mfma_f32_16x16x32_bf16(af[m], bfr[n], acc[m][n], 0, 0, 0);
        }
        __syncthreads();
    }

    // Epilogue. C/D layout: col = lane&15, row = (lane>>4)*4 + j
    const int r0 = bm * 128 + wr * 64 + l4 * 4;
    const int c0 = bn * 128 + wc * 64 + l16;
    if (MODE == 1) {
        float* Cf = (float*)Cv;
#pragma unroll
        for (int n = 0; n < 4; ++n) {
            const float bv = bias[c0 + n * 16];
#pragma unroll
            for (int m = 0; m < 4; ++m)
#pragma unroll
                for (int j = 0; j < 4; ++j)
                    Cf[(size_t)(r0 + m * 16 + j) * Ndim + c0 + n * 16] = acc[m][n][j] + bv;
        }
    } else if (MODE == 2 && bn >= 32) {
        // V columns: write transposed into vt[(b*16+h)*128 + d][t]
        const int h = bn - 32;
#pragma unroll
        for (int m = 0; m < 4; ++m) {
            const int r = r0 + m * 16;           // global row = b*2048 + t
            const int b = r >> 11, t0 = r & 2047;
#pragma unroll
            for (int n = 0; n < 4; ++n) {
                const int dcol = wc * 64 + n * 16 + l16;
                ushort* vp = vtout + (size_t)((b * 16 + h) * 128 + dcol) * TDIM + t0;
#pragma unroll
                for (int j = 0; j < 4; ++j)
                    vp[j] = f2bf(acc[m][n][j]);
            }
        }
    } else {
        // MODE 0, or MODE 2 Q/K columns (row stride QKS; Q columns pre-scaled by 1/sqrt(d))
        const int cstride = (MODE == 2) ? QKS : Ndim;
        const float sc = (MODE == 2 && bn < 16) ? 0.08838834764831845f : 1.0f;
        ushort* Cb = (ushort*)Cv;
#pragma unroll
        for (int n = 0; n < 4; ++n)
#pragma unroll
            for (int m = 0; m < 4; ++m)
#pragma unroll
                for (int j = 0; j < 4; ++j)
                    Cb[(size_t)(r0 + m * 16 + j) * cstride + c0 + n * 16] = f2bf(acc[m][n][j] * sc);
    }
}

// ---------------- Flash attention v4 (causal, split-row binning, V direct-from-L2) ----------
// qk [4096][4096] bf16 (Q pre-scaled, cols 0..2047; K cols 2048..4095); vt [bh][128][2048];
// ao [4096][2048]. K staged in LDS (dbuf); V read straight from global (L2-resident, m169).
// LDS 48 KiB -> 3 blocks/CU.
__global__ __launch_bounds__(256, 3) void flash_kernel(const ushort* __restrict__ qk,
                                                       const ushort* __restrict__ vt,
                                                       ushort* __restrict__ ao) {
    __shared__ __align__(16) ushort Kl[2][64 * 128];   // [kv][d], 16B d-chunks XOR-swizzled
    __shared__ __align__(16) ushort Pl[128 * 64];      // [slot][kv], XOR-swizzled

    const int xi = blockIdx.x;
    const int ti = (xi & 1) ? (xi >> 1) : (15 - (xi >> 1));  // heavy/light interleave
    const int h = blockIdx.y;
    const int b = blockIdx.z;
    const int tid = threadIdx.x;
    const int lane = tid & 63;
    const int wv = tid >> 6;
    const int l4 = lane >> 4, l16 = lane & 15;

    const int rbs[2]  = {ti * 64 + wv * 16, TDIM - 64 * (ti + 1) + wv * 16};  // block-local T rows
    const int diag[2] = {ti, 31 - ti};
    const int nkt = 32 - ti;

    // Q fragments (already scaled in GEMM1 epilogue). A-layout: row=lane&15, k=(lane>>4)*8+...
    v8bf qf[2][4];
#pragma unroll
    for (int mg = 0; mg < 2; ++mg) {
        const ushort* qp = qk + (size_t)(b * TDIM + rbs[mg] + l16) * QKS + h * HD + l4 * 8;
#pragma unroll
        for (int d0 = 0; d0 < 4; ++d0)
            qf[mg][d0] = *reinterpret_cast<const v8bf*>(qp + d0 * 32);
    }

    float mrun[2][4], lrun[2][4];
#pragma unroll
    for (int mg = 0; mg < 2; ++mg)
#pragma unroll
        for (int j = 0; j < 4; ++j) { mrun[mg][j] = -1e30f; lrun[mg][j] = 0.0f; }
    v4f oacc[2][8] = {};

    const ushort* kbase = qk + (size_t)(b * TDIM) * QKS + EDIM + h * HD;
    const ushort* vbase = vt + (size_t)((b * 16 + h) * HD) * TDIM;

#define STAGE(BUF, KT)                                                                        \
    do {                                                                                      \
        _Pragma("unroll") for (int i = 0; i < 4; ++i) {                                       \
            const int c = i * 256 + tid;                                                      \
            const int row = c >> 4;                                                           \
            const int dc = (c & 15) ^ (row & 7);                                              \
            gload16(kbase + (size_t)((KT) * 64 + row) * QKS + dc * 8,                         \
                    &Kl[BUF][(i * 256 + wv * 64) * 8]);                                       \
        }                                                                                     \
    } while (0)

    STAGE(0, 0);
    __syncthreads();
    int cur = 0;

    for (int kt = 0; kt < nkt; ++kt) {
        if (kt + 1 < nkt) STAGE(cur ^ 1, kt + 1);   // prefetch K overlaps compute

        const bool act0 = (kt <= diag[0]);          // mg0 active until its diagonal
        const ushort* Kb = &Kl[cur][0];

        // ---- S = Q @ K^T ----
        v4f s[2][4] = {};
#pragma unroll
        for (int d0 = 0; d0 < 4; ++d0) {
            v8bf kf[4];
#pragma unroll
            for (int kvn = 0; kvn < 4; ++kvn) {
                const int r = kvn * 16 + l16;
                const int slot = (d0 * 4 + l4) ^ (r & 7);
                kf[kvn] = *reinterpret_cast<const v8bf*>(&Kb[r * 128 + slot * 8]);
            }
#pragma unroll
            for (int kvn = 0; kvn < 4; ++kvn) {
                if (act0)
                    s[0][kvn] = __builtin_amdgcn_mfma_f32_16x16x32_bf16(qf[0][d0], kf[kvn], s[0][kvn], 0, 0, 0);
                s[1][kvn] = __builtin_amdgcn_mfma_f32_16x16x32_bf16(qf[1][d0], kf[kvn], s[1][kvn], 0, 0, 0);
            }
        }

        // ---- per-group softmax + P write ----
#pragma unroll
        for (int mg = 0; mg < 2; ++mg) {
            if (mg == 0 && !act0) continue;

            float sv[4][4];
#pragma unroll
            for (int kvn = 0; kvn < 4; ++kvn)
#pragma unroll
                for (int j = 0; j < 4; ++j)
                    sv[kvn][j] = s[mg][kvn][j];

            if (kt == diag[mg]) {  // diagonal tile mask (block-local T coords)
                const int rg = rbs[mg] + l4 * 4;
#pragma unroll
                for (int kvn = 0; kvn < 4; ++kvn) {
                    const int cg = kt * 64 + kvn * 16 + l16;
#pragma unroll
                    for (int j = 0; j < 4; ++j)
                        if (cg > rg + j) sv[kvn][j] = -__builtin_inff();
                }
            }

            // row max (row spans the 16-lane group)
            float pm[4], dmax = -1e30f;
#pragma unroll
            for (int j = 0; j < 4; ++j) {
                float m0 = fmaxf(fmaxf(sv[0][j], sv[1][j]), fmaxf(sv[2][j], sv[3][j]));
                m0 = fmaxf(m0, __shfl_xor(m0, 1));
                m0 = fmaxf(m0, __shfl_xor(m0, 2));
                m0 = fmaxf(m0, __shfl_xor(m0, 4));
                m0 = fmaxf(m0, __shfl_xor(m0, 8));
                pm[j] = m0;
                dmax = fmaxf(dmax, m0 - mrun[mg][j]);
            }
            if (!__all(dmax <= 8.0f)) {   // T13 defer-max: rescale only when needed
                float corr[4];
#pragma unroll
                for (int j = 0; j < 4; ++j) {
                    const float mn = fmaxf(mrun[mg][j], pm[j]);
                    corr[j] = __expf(mrun[mg][j] - mn);
                    mrun[mg][j] = mn;
                    lrun[mg][j] *= corr[j];
                }
#pragma unroll
                for (int n = 0; n < 8; ++n)
#pragma unroll
                    for (int j = 0; j < 4; ++j)
                        oacc[mg][n][j] *= corr[j];
            }

            float p[4][4];
#pragma unroll
            for (int kvn = 0; kvn < 4; ++kvn)
#pragma unroll
                for (int j = 0; j < 4; ++j)
                    p[kvn][j] = __expf(sv[kvn][j] - mrun[mg][j]);
#pragma unroll
            for (int j = 0; j < 4; ++j)
                lrun[mg][j] += p[0][j] + p[1][j] + p[2][j] + p[3][j];

            // P -> LDS (swizzled), same-wave slots only (wave-local: no barrier needed)
            const int row = wv * 32 + mg * 16 + l4 * 4;
#pragma unroll
            for (int kvn = 0; kvn < 4; ++kvn) {
                const int cc = kvn * 2 + (l16 >> 3);
#pragma unroll
                for (int j = 0; j < 4; ++j) {
                    const int r = row + j;
                    Pl[r * 64 + ((cc ^ (r & 7)) * 8) + (l16 & 7)] = f2bf(p[kvn][j]);
                }
            }
        }

        // ---- O += P @ V (V fragments straight from global; L2-resident, 16B contiguous) ----
#pragma unroll
        for (int kk = 0; kk < 2; ++kk) {
            v8bf pf[2];
#pragma unroll
            for (int mg = 0; mg < 2; ++mg) {
                if (mg == 0 && !act0) continue;
                const int r = wv * 32 + mg * 16 + l16;
                const int slot = (kk * 4 + l4) ^ (r & 7);
                pf[mg] = *reinterpret_cast<const v8bf*>(&Pl[r * 64 + slot * 8]);
            }
#pragma unroll
            for (int n = 0; n < 8; ++n) {
                const v8bf vf = *reinterpret_cast<const v8bf*>(
                    vbase + (size_t)(n * 16 + l16) * TDIM + kt * 64 + kk * 32 + l4 * 8);
                if (act0)
                    oacc[0][n] = __builtin_amdgcn_mfma_f32_16x16x32_bf16(pf[0], vf, oacc[0][n], 0, 0, 0);
                oacc[1][n] = __builtin_amdgcn_mfma_f32_16x16x32_bf16(pf[1], vf, oacc[1][n], 0, 0, 0);
            }
        }
        __syncthreads();
        cur ^= 1;
    }
#undef STAGE

    // ---- epilogue: finish l reduction, normalize, store ----
#pragma unroll
    for (int mg = 0; mg < 2; ++mg) {
        float inv[4];
#pragma unroll
        for (int j = 0; j < 4; ++j) {
            float l = lrun[mg][j];
            l += __shfl_xor(l, 1);
            l += __shfl_xor(l, 2);
            l += __shfl_xor(l, 4);
            l += __shfl_xor(l, 8);
            inv[j] = 1.0f / l;
        }
        ushort* aop = ao + (size_t)(b * TDIM + rbs[mg] + l4 * 4) * EDIM + h * HD + l16;
#pragma unroll
        for (int n = 0; n < 8; ++n)
#pragma unroll
            for (int j = 0; j < 4; ++j)
                aop[(size_t)j * EDIM + n * 16] = f2bf(oacc[mg][n][j] * inv[j]);
    }
}

// ---------------- launcher ----------------
extern "C" void kernel_launch(void* const* d_in, const int* in_sizes, int n_in,
                              void* d_out, int out_size, void* d_ws, size_t ws_size,
                              hipStream_t stream) {
    (void)in_sizes; (void)n_in; (void)out_size; (void)ws_size;
    const float* x     = (const float*)d_in[0];
    const float* w_qkv = (const float*)d_in[1];
    const float* w_out = (const float*)d_in[2];
    const float* b_out = (const float*)d_in[3];

    uint8_t* ws = (uint8_t*)d_ws;
    // layout (bytes):
    //   qk    @ 0         : 4096*4096*2 = 33554432   (Q|K, row stride 4096; Q pre-scaled)
    //   vt    @ 33554432  : 32*128*2048*2 = 16777216 (V transposed per head)
    //   woutT @ 50331648  : 2048*2048*2 =  8388608
    //   xb    @ 58720256  : 4096*2048*2 = 16777216
    //   wqkvT @ 75497472  : 6144*2048*2 = 25165824   (aliased by ao after GEMM1)
    ushort* qk    = (ushort*)(ws);
    ushort* vtb   = (ushort*)(ws + 33554432u);
    ushort* woutT = (ushort*)(ws + 50331648u);
    ushort* xb    = (ushort*)(ws + 58720256u);
    ushort* wqkvT = (ushort*)(ws + 75497472u);
    ushort* ao    = wqkvT;  // reuse after GEMM1 consumed wqkvT

    prep_kernel<<<NB_T1 + NB_T2 + NB_CV, 256, 0, stream>>>(x, w_qkv, w_out, xb, wqkvT, woutT);

    gemm_kernel<2><<<(MROWS / 128) * (E3 / 128), 256, 0, stream>>>(
        xb, wqkvT, (void*)qk, nullptr, vtb, MROWS, E3, EDIM);

    flash_kernel<<<dim3(16, NH, BATCH), 256, 0, stream>>>(qk, vtb, ao);

    gemm_kernel<1><<<(MROWS / 128) * (EDIM / 128), 256, 0, stream>>>(
        ao, woutT, d_out, b_out, nullptr, MROWS, EDIM, EDIM);
}

// Round 10
// 256.328 us; speedup vs baseline: 2.3178x; 2.3178x over previous
//
#include <hip/hip_runtime.h>
#include <stdint.h>

// Problem constants
#define BATCH 2
#define TDIM 2048
#define EDIM 2048
#define NH 16
#define HD 128
#define E3 6144
#define MROWS 4096  // BATCH*TDIM
#define QKS 4096    // row stride of compacted Q|K buffer

typedef short v8bf __attribute__((ext_vector_type(8)));   // 8 bf16 bit patterns (4 VGPRs)
typedef float v4f  __attribute__((ext_vector_type(4)));

typedef __attribute__((address_space(3))) uint8_t lds_u8;
typedef __attribute__((address_space(1))) uint8_t glb_u8;

__device__ __forceinline__ void gload16(const void* g, void* l) {
    __builtin_amdgcn_global_load_lds((const glb_u8*)g, (lds_u8*)l, 16, 0, 0);
}

__device__ __forceinline__ ushort f2bf(float f) {
    uint32_t u = __float_as_uint(f);
    return (ushort)((u + 0x7fffu + ((u >> 16) & 1u)) >> 16);  // RNE
}

// ---------------- fused preprocessing: tcvt(w_qkv) + tcvt(w_out) + cvtx(x) ----------------
__device__ __forceinline__ void tcvt_body(const float* __restrict__ in, ushort* __restrict__ out,
                                          int R, int C, int tcb, int trb, int tid) {
    __shared__ float t[32][33];
    const int tc = tcb * 32, tr = trb * 32;
    const int row = tid >> 3, c4 = (tid & 7) * 4;
    const float4 v = *reinterpret_cast<const float4*>(in + (size_t)(tr + row) * C + tc + c4);
    t[row][c4] = v.x; t[row][c4 + 1] = v.y; t[row][c4 + 2] = v.z; t[row][c4 + 3] = v.w;
    __syncthreads();
    const int oc = tid >> 3, r4 = (tid & 7) * 4;
    ushort4 o = make_ushort4(f2bf(t[r4][oc]), f2bf(t[r4 + 1][oc]),
                             f2bf(t[r4 + 2][oc]), f2bf(t[r4 + 3][oc]));
    *reinterpret_cast<ushort4*>(out + (size_t)(tc + oc) * R + tr + r4) = o;
}

#define NB_T1 12288   // (6144/32)*(2048/32)
#define NB_T2 4096    // (2048/32)*(2048/32)
#define NB_CV 2048

__global__ void prep_kernel(const float* __restrict__ x, const float* __restrict__ w_qkv,
                            const float* __restrict__ w_out, ushort* __restrict__ xb,
                            ushort* __restrict__ wqkvT, ushort* __restrict__ woutT) {
    const int bid = blockIdx.x;
    const int tid = threadIdx.x;
    if (bid < NB_T1) {
        tcvt_body(w_qkv, wqkvT, EDIM, E3, bid % (E3 / 32), bid / (E3 / 32), tid);
    } else if (bid < NB_T1 + NB_T2) {
        const int b2 = bid - NB_T1;
        tcvt_body(w_out, woutT, EDIM, EDIM, b2 % (EDIM / 32), b2 / (EDIM / 32), tid);
    } else {
        const int b3 = bid - NB_T1 - NB_T2;
        int i = (b3 * 256 + tid) * 4;
        const int stride = NB_CV * 256 * 4;
        const int n = MROWS * EDIM;
        for (; i < n; i += stride) {
            const float4 v = *reinterpret_cast<const float4*>(x + i);
            ushort4 o = make_ushort4(f2bf(v.x), f2bf(v.y), f2bf(v.z), f2bf(v.w));
            *reinterpret_cast<ushort4*>(xb + i) = o;
        }
    }
}

// ---------------- bf16 GEMM (128x128, m97-structure, proven 892 TF) ----------------
// MODE 0: bf16 C. MODE 1: f32 C + bias. MODE 2: qkv-split -> Q (pre-scaled by 1/sqrt(d)), K
//         cols to qk (stride QKS), V cols (bn>=32) transposed per-head into vt[bh][d][t].
template <int MODE>
__global__ void gemm_kernel(const ushort* __restrict__ A, const ushort* __restrict__ Bt,
                            void* __restrict__ Cv, const float* __restrict__ bias,
                            ushort* __restrict__ vtout,
                            int Mdim, int Ndim, int Kdim) {
    __shared__ __align__(16) ushort As[128 * 64];
    __shared__ __align__(16) ushort Bs[128 * 64];
    const int tid = threadIdx.x;
    const int lane = tid & 63;
    const int wv = tid >> 6;
    const int l4 = lane >> 4, l16 = lane & 15;
    const int nbn = Ndim >> 7;
    const int nwg = (Mdim >> 7) * nbn;
    int bid = blockIdx.x;
    bid = (bid & 7) * (nwg >> 3) + (bid >> 3);   // XCD swizzle (nwg % 8 == 0)
    const int bm = bid / nbn, bn = bid % nbn;
    const int wr = wv >> 1, wc = wv & 1;

    const ushort* Abase = A + (size_t)(bm * 128) * Kdim;
    const ushort* Bbase = Bt + (size_t)(bn * 128) * Kdim;

    v4f acc[4][4] = {};

    for (int k0 = 0; k0 < Kdim; k0 += 64) {
#pragma unroll
        for (int i = 0; i < 4; ++i) {
            const int c = i * 256 + tid;
            const int row = c >> 3;
            const int kc = (c & 7) ^ (row & 7);    // pre-swizzled global source
            gload16(Abase + (size_t)row * Kdim + k0 + kc * 8, &As[(i * 256 + wv * 64) * 8]);
        }
#pragma unroll
        for (int i = 0; i < 4; ++i) {
            const int c = i * 256 + tid;
            const int row = c >> 3;
            const int kc = (c & 7) ^ (row & 7);
            gload16(Bbase + (size_t)row * Kdim + k0 + kc * 8, &Bs[(i * 256 + wv * 64) * 8]);
        }
        __syncthreads();
#pragma unroll
        for (int kk = 0; kk < 2; ++kk) {
            v8bf af[4], bfr[4];
#pragma unroll
            for (int m = 0; m < 4; ++m) {
                const int r = wr * 64 + m * 16 + l16;
                const int slot = (kk * 4 + l4) ^ (r & 7);
                af[m] = *reinterpret_cast<const v8bf*>(&As[r * 64 + slot * 8]);
            }
#pragma unroll
            for (int n = 0; n < 4; ++n) {
                const int r = wc * 64 + n * 16 + l16;
                const int slot = (kk * 4 + l4) ^ (r & 7);
                bfr[n] = *reinterpret_cast<const v8bf*>(&Bs[r * 64 + slot * 8]);
            }
#pragma unroll
            for (int m = 0; m < 4; ++m)
#pragma unroll
                for (int n = 0; n < 4; ++n)
                    acc[m][n] = __builtin_amdgcn_mfma_f32_16x16x32_bf16(af[m], bfr[n], acc[m][n], 0, 0, 0);
        }
        __syncthreads();
    }

    // Epilogue. C/D layout: col = lane&15, row = (lane>>4)*4 + j
    const int r0 = bm * 128 + wr * 64 + l4 * 4;
    const int c0 = bn * 128 + wc * 64 + l16;
    if (MODE == 1) {
        float* Cf = (float*)Cv;
#pragma unroll
        for (int n = 0; n < 4; ++n) {
            const float bv = bias[c0 + n * 16];
#pragma unroll
            for (int m = 0; m < 4; ++m)
#pragma unroll
                for (int j = 0; j < 4; ++j)
                    Cf[(size_t)(r0 + m * 16 + j) * Ndim + c0 + n * 16] = acc[m][n][j] + bv;
        }
    } else if (MODE == 2 && bn >= 32) {
        // V columns: write transposed into vt[(b*16+h)*128 + d][t]
        const int h = bn - 32;
#pragma unroll
        for (int m = 0; m < 4; ++m) {
            const int r = r0 + m * 16;           // global row = b*2048 + t
            const int b = r >> 11, t0 = r & 2047;
#pragma unroll
            for (int n = 0; n < 4; ++n) {
                const int dcol = wc * 64 + n * 16 + l16;
                ushort* vp = vtout + (size_t)((b * 16 + h) * 128 + dcol) * TDIM + t0;
#pragma unroll
                for (int j = 0; j < 4; ++j)
                    vp[j] = f2bf(acc[m][n][j]);
            }
        }
    } else {
        // MODE 0, or MODE 2 Q/K columns (row stride QKS; Q columns pre-scaled by 1/sqrt(d))
        const int cstride = (MODE == 2) ? QKS : Ndim;
        const float sc = (MODE == 2 && bn < 16) ? 0.08838834764831845f : 1.0f;
        ushort* Cb = (ushort*)Cv;
#pragma unroll
        for (int n = 0; n < 4; ++n)
#pragma unroll
            for (int m = 0; m < 4; ++m)
#pragma unroll
                for (int j = 0; j < 4; ++j)
                    Cb[(size_t)(r0 + m * 16 + j) * cstride + c0 + n * 16] = f2bf(acc[m][n][j] * sc);
    }
}

// ---------------- Flash attention v3 (causal, balanced split-row binning; R7-proven) --------
// qk [4096][4096] bf16 (Q pre-scaled, cols 0..2047; K cols 2048..4095); vt [bh][128][2048];
// ao [4096][2048]. K,V double-buffered in LDS, P swizzled; 80 KiB -> 2 blocks/CU.
__global__ __launch_bounds__(256, 2) void flash_kernel(const ushort* __restrict__ qk,
                                                       const ushort* __restrict__ vt,
                                                       ushort* __restrict__ ao) {
    __shared__ __align__(16) ushort Kl[2][64 * 128];   // [kv][d], 16B d-chunks XOR-swizzled
    __shared__ __align__(16) ushort Vl[2][128 * 64];   // [d][kv], 16B kv-chunks XOR-swizzled
    __shared__ __align__(16) ushort Pl[128 * 64];      // [slot][kv], XOR-swizzled

    const int xi = blockIdx.x;
    const int ti = (xi & 1) ? (xi >> 1) : (15 - (xi >> 1));  // heavy/light interleave
    const int h = blockIdx.y;
    const int b = blockIdx.z;
    const int tid = threadIdx.x;
    const int lane = tid & 63;
    const int wv = tid >> 6;
    const int l4 = lane >> 4, l16 = lane & 15;

    const int rbs[2]  = {ti * 64 + wv * 16, TDIM - 64 * (ti + 1) + wv * 16};  // block-local T rows
    const int diag[2] = {ti, 31 - ti};
    const int nkt = 32 - ti;

    // Q fragments (pre-scaled in GEMM1 epilogue). A-layout: row=lane&15, k=(lane>>4)*8+...
    v8bf qf[2][4];
#pragma unroll
    for (int mg = 0; mg < 2; ++mg) {
        const ushort* qp = qk + (size_t)(b * TDIM + rbs[mg] + l16) * QKS + h * HD + l4 * 8;
#pragma unroll
        for (int d0 = 0; d0 < 4; ++d0)
            qf[mg][d0] = *reinterpret_cast<const v8bf*>(qp + d0 * 32);
    }

    float mrun[2][4], lrun[2][4];
#pragma unroll
    for (int mg = 0; mg < 2; ++mg)
#pragma unroll
        for (int j = 0; j < 4; ++j) { mrun[mg][j] = -1e30f; lrun[mg][j] = 0.0f; }
    v4f oacc[2][8] = {};

    const ushort* kbase = qk + (size_t)(b * TDIM) * QKS + EDIM + h * HD;
    const ushort* vbase = vt + (size_t)((b * 16 + h) * HD) * TDIM;

#define STAGE(BUF, KT)                                                                        \
    do {                                                                                      \
        _Pragma("unroll") for (int i = 0; i < 4; ++i) {                                       \
            const int c = i * 256 + tid;                                                      \
            const int row = c >> 4;                                                           \
            const int dc = (c & 15) ^ (row & 7);                                              \
            gload16(kbase + (size_t)((KT) * 64 + row) * QKS + dc * 8,                         \
                    &Kl[BUF][(i * 256 + wv * 64) * 8]);                                       \
        }                                                                                     \
        _Pragma("unroll") for (int i = 0; i < 4; ++i) {                                       \
            const int c = i * 256 + tid;                                                      \
            const int row = c >> 3;                                                           \
            const int jc = (c & 7) ^ (row & 7);                                               \
            gload16(vbase + (size_t)row * TDIM + (KT) * 64 + jc * 8,                          \
                    &Vl[BUF][(i * 256 + wv * 64) * 8]);                                       \
        }                                                                                     \
    } while (0)

    STAGE(0, 0);
    __syncthreads();
    int cur = 0;

    for (int kt = 0; kt < nkt; ++kt) {
        if (kt + 1 < nkt) STAGE(cur ^ 1, kt + 1);   // prefetch overlaps compute

        const bool act0 = (kt <= diag[0]);          // mg0 active until its diagonal
        const ushort* Kb = &Kl[cur][0];
        const ushort* Vb = &Vl[cur][0];

        // ---- S = Q @ K^T ----
        v4f s[2][4] = {};
#pragma unroll
        for (int d0 = 0; d0 < 4; ++d0) {
            v8bf kf[4];
#pragma unroll
            for (int kvn = 0; kvn < 4; ++kvn) {
                const int r = kvn * 16 + l16;
                const int slot = (d0 * 4 + l4) ^ (r & 7);
                kf[kvn] = *reinterpret_cast<const v8bf*>(&Kb[r * 128 + slot * 8]);
            }
#pragma unroll
            for (int kvn = 0; kvn < 4; ++kvn) {
                if (act0)
                    s[0][kvn] = __builtin_amdgcn_mfma_f32_16x16x32_bf16(qf[0][d0], kf[kvn], s[0][kvn], 0, 0, 0);
                s[1][kvn] = __builtin_amdgcn_mfma_f32_16x16x32_bf16(qf[1][d0], kf[kvn], s[1][kvn], 0, 0, 0);
            }
        }

        // ---- per-group softmax + P write ----
#pragma unroll
        for (int mg = 0; mg < 2; ++mg) {
            if (mg == 0 && !act0) continue;

            float sv[4][4];
#pragma unroll
            for (int kvn = 0; kvn < 4; ++kvn)
#pragma unroll
                for (int j = 0; j < 4; ++j)
                    sv[kvn][j] = s[mg][kvn][j];

            if (kt == diag[mg]) {  // diagonal tile mask (block-local T coords)
                const int rg = rbs[mg] + l4 * 4;
#pragma unroll
                for (int kvn = 0; kvn < 4; ++kvn) {
                    const int cg = kt * 64 + kvn * 16 + l16;
#pragma unroll
                    for (int j = 0; j < 4; ++j)
                        if (cg > rg + j) sv[kvn][j] = -__builtin_inff();
                }
            }

            // row max (row spans the 16-lane group)
            float pm[4], dmax = -1e30f;
#pragma unroll
            for (int j = 0; j < 4; ++j) {
                float m0 = fmaxf(fmaxf(sv[0][j], sv[1][j]), fmaxf(sv[2][j], sv[3][j]));
                m0 = fmaxf(m0, __shfl_xor(m0, 1));
                m0 = fmaxf(m0, __shfl_xor(m0, 2));
                m0 = fmaxf(m0, __shfl_xor(m0, 4));
                m0 = fmaxf(m0, __shfl_xor(m0, 8));
                pm[j] = m0;
                dmax = fmaxf(dmax, m0 - mrun[mg][j]);
            }
            if (!__all(dmax <= 8.0f)) {   // T13 defer-max: rescale only when needed
                float corr[4];
#pragma unroll
                for (int j = 0; j < 4; ++j) {
                    const float mn = fmaxf(mrun[mg][j], pm[j]);
                    corr[j] = __expf(mrun[mg][j] - mn);
                    mrun[mg][j] = mn;
                    lrun[mg][j] *= corr[j];
                }
#pragma unroll
                for (int n = 0; n < 8; ++n)
#pragma unroll
                    for (int j = 0; j < 4; ++j)
                        oacc[mg][n][j] *= corr[j];
            }

            float p[4][4];
#pragma unroll
            for (int kvn = 0; kvn < 4; ++kvn)
#pragma unroll
                for (int j = 0; j < 4; ++j)
                    p[kvn][j] = __expf(sv[kvn][j] - mrun[mg][j]);
#pragma unroll
            for (int j = 0; j < 4; ++j)
                lrun[mg][j] += p[0][j] + p[1][j] + p[2][j] + p[3][j];

            // P -> LDS (swizzled), same-wave slots only
            const int row = wv * 32 + mg * 16 + l4 * 4;
#pragma unroll
            for (int kvn = 0; kvn < 4; ++kvn) {
                const int cc = kvn * 2 + (l16 >> 3);
#pragma unroll
                for (int j = 0; j < 4; ++j) {
                    const int r = row + j;
                    Pl[r * 64 + ((cc ^ (r & 7)) * 8) + (l16 & 7)] = f2bf(p[kvn][j]);
                }
            }
        }

        // ---- O += P @ V ----
#pragma unroll
        for (int kk = 0; kk < 2; ++kk) {
            v8bf pf[2];
#pragma unroll
            for (int mg = 0; mg < 2; ++mg) {
                if (mg == 0 && !act0) continue;
                const int r = wv * 32 + mg * 16 + l16;
                const int slot = (kk * 4 + l4) ^ (r & 7);
                pf[mg] = *reinterpret_cast<const v8bf*>(&Pl[r * 64 + slot * 8]);
            }
#pragma unroll
            for (int n = 0; n < 8; ++n) {
                const int dr = n * 16 + l16;
                const int slot = (kk * 4 + l4) ^ (dr & 7);
                v8bf vf = *reinterpret_cast<const v8bf*>(&Vb[dr * 64 + slot * 8]);
                if (act0)
                    oacc[0][n] = __builtin_amdgcn_mfma_f32_16x16x32_bf16(pf[0], vf, oacc[0][n], 0, 0, 0);
                oacc[1][n] = __builtin_amdgcn_mfma_f32_16x16x32_bf16(pf[1], vf, oacc[1][n], 0, 0, 0);
            }
        }
        __syncthreads();
        cur ^= 1;
    }
#undef STAGE

    // ---- epilogue: finish l reduction, normalize, store ----
#pragma unroll
    for (int mg = 0; mg < 2; ++mg) {
        float inv[4];
#pragma unroll
        for (int j = 0; j < 4; ++j) {
            float l = lrun[mg][j];
            l += __shfl_xor(l, 1);
            l += __shfl_xor(l, 2);
            l += __shfl_xor(l, 4);
            l += __shfl_xor(l, 8);
            inv[j] = 1.0f / l;
        }
        ushort* aop = ao + (size_t)(b * TDIM + rbs[mg] + l4 * 4) * EDIM + h * HD + l16;
#pragma unroll
        for (int n = 0; n < 8; ++n)
#pragma unroll
            for (int j = 0; j < 4; ++j)
                aop[(size_t)j * EDIM + n * 16] = f2bf(oacc[mg][n][j] * inv[j]);
    }
}

// ---------------- launcher ----------------
extern "C" void kernel_launch(void* const* d_in, const int* in_sizes, int n_in,
                              void* d_out, int out_size, void* d_ws, size_t ws_size,
                              hipStream_t stream) {
    (void)in_sizes; (void)n_in; (void)out_size; (void)ws_size;
    const float* x     = (const float*)d_in[0];
    const float* w_qkv = (const float*)d_in[1];
    const float* w_out = (const float*)d_in[2];
    const float* b_out = (const float*)d_in[3];

    uint8_t* ws = (uint8_t*)d_ws;
    // layout (bytes):
    //   qk    @ 0         : 4096*4096*2 = 33554432   (Q|K, row stride 4096; Q pre-scaled)
    //   vt    @ 33554432  : 32*128*2048*2 = 16777216 (V transposed per head)
    //   woutT @ 50331648  : 2048*2048*2 =  8388608
    //   xb    @ 58720256  : 4096*2048*2 = 16777216
    //   wqkvT @ 75497472  : 6144*2048*2 = 25165824   (aliased by ao after GEMM1)
    ushort* qk    = (ushort*)(ws);
    ushort* vtb   = (ushort*)(ws + 33554432u);
    ushort* woutT = (ushort*)(ws + 50331648u);
    ushort* xb    = (ushort*)(ws + 58720256u);
    ushort* wqkvT = (ushort*)(ws + 75497472u);
    ushort* ao    = wqkvT;  // reuse after GEMM1 consumed wqkvT

    prep_kernel<<<NB_T1 + NB_T2 + NB_CV, 256, 0, stream>>>(x, w_qkv, w_out, xb, wqkvT, woutT);

    gemm_kernel<2><<<(MROWS / 128) * (E3 / 128), 256, 0, stream>>>(
        xb, wqkvT, (void*)qk, nullptr, vtb, MROWS, E3, EDIM);

    flash_kernel<<<dim3(16, NH, BATCH), 256, 0, stream>>>(qk, vtb, ao);

    gemm_kernel<1><<<(MROWS / 128) * (EDIM / 128), 256, 0, stream>>>(
        ao, woutT, d_out, b_out, nullptr, MROWS, EDIM, EDIM);
}